// Round 3
// baseline (254.300 us; speedup 1.0000x reference)
//
#include <hip/hip_runtime.h>
#include <hip/hip_bf16.h>
#include <stdint.h>

typedef __bf16 bf16;
typedef __bf16 bf16x8 __attribute__((ext_vector_type(8)));
typedef __bf16 bf16x4 __attribute__((ext_vector_type(4)));
typedef float f32x4 __attribute__((ext_vector_type(4)));
typedef float f32x8 __attribute__((ext_vector_type(8)));

#define BB 32
#define TT 2048
#define DD 1024
#define HH 128
#define SCALE 0.08838834764831845f   // H^-0.5
#define LOG2E 1.4426950408889634f
#define KS (SCALE * LOG2E)

__device__ __forceinline__ void gl_lds16(const bf16* g, bf16* l) {
  __builtin_amdgcn_global_load_lds((__attribute__((address_space(1))) const void*)g,
                                   (__attribute__((address_space(3))) void*)l,
                                   16, 0, 0);
}

// ---------------- kernel 0: Wt[mat][h][d] = W[d][h] (fp32 -> bf16) -------------
// mat 0 (Wk) pre-scaled by SCALE*LOG2E so softmax runs in exp2 domain with no
// extra multiplies. Also emits concatenated fp32 bias bcat[384] (bk scaled).
__global__ __launch_bounds__(256) void prep_w(const float* __restrict__ Wk,
                                              const float* __restrict__ Wq,
                                              const float* __restrict__ Wv,
                                              const float* __restrict__ bk,
                                              const float* __restrict__ bq,
                                              const float* __restrict__ bv,
                                              bf16* __restrict__ Wt,
                                              float* __restrict__ bcat) {
  int tid = blockIdx.x * 256 + threadIdx.x;   // 0..49151
  if (tid < 384) {
    int mat = tid >> 7, h = tid & 127;
    float bb = (mat == 0) ? bk[h] : (mat == 1) ? bq[h] : bv[h];
    bcat[tid] = (mat == 0) ? bb * KS : bb;
  }
  int mat = tid >> 14;
  int r = tid & 16383;
  int h = r & 127;
  int d0 = (r >> 7) << 3;
  const float* W = (mat == 0) ? Wk : (mat == 1) ? Wq : Wv;
  const float ks = (mat == 0) ? KS : 1.0f;
  bf16x8 v;
#pragma unroll
  for (int i = 0; i < 8; ++i) v[i] = (bf16)(W[(size_t)(d0 + i) * HH + h] * ks);
  *(bf16x8*)(Wt + ((size_t)mat * HH + h) * DD + d0) = v;
}

// ---------------- kernel 1: fused QKV projection GEMM (bf16 MFMA) --------------
// ONE pass over x: block = 64 rows x 384 cols (cols = [k|q|v]), 1024 blocks.
// A (x) staged in LDS (bf16, XOR-swizzled, double-buffered, BK=64);
// B (Wt) fragments read directly from global (768 KB total, L1/L2-resident).
// 4 waves, wave tile 64x96 (4 m-frags x 6 n-frags).
__global__ __launch_bounds__(256, 3) void qkv_proj(
    const float* __restrict__ x, const bf16* __restrict__ Wt,
    const float* __restrict__ bcat,
    bf16* __restrict__ kb, bf16* __restrict__ qb, bf16* __restrict__ Vt) {
  const int bid = blockIdx.x;
  const int tid = threadIdx.x;
  const int lane = tid & 63;
  const int w = tid >> 6;                    // wave id = N-tile
  const int l15 = lane & 15, l4 = lane >> 4;
  const size_t row0 = (size_t)bid * 64;
  const int colbase = w * 96;

  __shared__ __attribute__((aligned(16))) bf16 As[2][64][64];

  // staging coords: 2 iters x 256 threads = 512 chunks = 64 rows x 8 chunks
  const int sr0 = tid >> 3, sc0 = tid & 7;           // iter 0
  const int sr1 = (256 + tid) >> 3, sc1 = tid & 7;   // iter 1

  f32x4 acc[4][6];
#pragma unroll
  for (int m = 0; m < 4; ++m)
#pragma unroll
    for (int n = 0; n < 6; ++n) acc[m][n] = f32x4{0.f, 0.f, 0.f, 0.f};

  auto cvt_store = [&](int buf, f32x8 a, int r, int c) {
    bf16x8 t;
#pragma unroll
    for (int i = 0; i < 8; ++i) t[i] = (bf16)a[i];
    *(bf16x8*)&As[buf][r][(c ^ (r & 7)) * 8] = t;
  };

  // prologue: stage k0=0 into buf 0
  {
    f32x8 a0 = *(const f32x8*)(x + (row0 + sr0) * DD + sc0 * 8);
    f32x8 a1 = *(const f32x8*)(x + (row0 + sr1) * DD + sc1 * 8);
    cvt_store(0, a0, sr0, sc0);
    cvt_store(0, a1, sr1, sc1);
  }
  __syncthreads();

  for (int step = 0; step < 16; ++step) {
    const int k0 = step * 64;
    const int cur = step & 1;

    // issue next-tile global loads early (consumed after MFMAs)
    f32x8 n0, n1;
    if (step < 15) {
      n0 = *(const f32x8*)(x + (row0 + sr0) * DD + k0 + 64 + sc0 * 8);
      n1 = *(const f32x8*)(x + (row0 + sr1) * DD + k0 + 64 + sc1 * 8);
    }

#pragma unroll
    for (int kc = 0; kc < 2; ++kc) {
      bf16x8 af[4];
#pragma unroll
      for (int m = 0; m < 4; ++m) {
        int r = m * 16 + l15;
        af[m] = *(const bf16x8*)&As[cur][r][((kc * 4 + l4) ^ (r & 7)) * 8];
      }
      bf16x8 bfr[6];
#pragma unroll
      for (int n = 0; n < 6; ++n)
        bfr[n] = *(const bf16x8*)(Wt + (size_t)(colbase + n * 16 + l15) * DD +
                                  k0 + kc * 32 + l4 * 8);
#pragma unroll
      for (int m = 0; m < 4; ++m)
#pragma unroll
        for (int n = 0; n < 6; ++n)
          acc[m][n] = __builtin_amdgcn_mfma_f32_16x16x32_bf16(af[m], bfr[n],
                                                              acc[m][n], 0, 0, 0);
    }

    if (step < 15) {
      cvt_store(cur ^ 1, n0, sr0, sc0);
      cvt_store(cur ^ 1, n1, sr1, sc1);
    }
    __syncthreads();
  }

  // epilogue
  float bvv[6];
#pragma unroll
  for (int n = 0; n < 6; ++n) bvv[n] = bcat[colbase + n * 16 + l15];

  const int bidx = bid >> 5;
  const int tloc0 = (bid & 31) * 64;
#pragma unroll
  for (int m = 0; m < 4; ++m)
#pragma unroll
    for (int n = 0; n < 6; ++n) {
      int col = colbase + n * 16 + l15;
      int mat = col >> 7;
      int hcol = col & 127;
      if (mat == 2) {
        bf16x4 v4;
#pragma unroll
        for (int e = 0; e < 4; ++e) v4[e] = (bf16)(acc[m][n][e] + bvv[n]);
        int t = tloc0 + m * 16 + l4 * 4;
        *(bf16x4*)(Vt + ((size_t)bidx * HH + hcol) * TT + t) = v4;
      } else {
        bf16* dst = (mat == 0) ? kb : qb;
#pragma unroll
        for (int e = 0; e < 4; ++e) {
          size_t rowg = row0 + m * 16 + l4 * 4 + e;
          dst[rowg * HH + hcol] = (bf16)(acc[m][n][e] + bvv[n]);
        }
      }
    }
}

// ---------------- kernel 2: fused causal flash attention -----------------------
// quirk: scores[t][s] = k[t].q[s] -> k rows are the softmax rows (k pre-scaled
// by SCALE*LOG2E, so softmax is computed with exp2 directly).
// grid 512; block 256 = 4 waves * 16 rows = 64-row t-tile.
// Each block runs TWO complementary jobs: tiles (31-p) and (p) -> exactly
// 33 s-iterations per block (perfect balance), all 512 blocks co-resident.
__global__ __launch_bounds__(256, 3) void attn(const bf16* __restrict__ kb,
                                               const bf16* __restrict__ qb,
                                               const bf16* __restrict__ Vt,
                                               float* __restrict__ out) {
  const int bid = blockIdx.x;
  const int b = bid & 31;
  const int p = bid >> 5;                 // 0..15
  const int tid = threadIdx.x;
  const int lane = tid & 63;
  const int w = tid >> 6;
  const int l15 = lane & 15, l4 = lane >> 4;

  __shared__ __attribute__((aligned(16))) bf16 Es[64 * 128];   // q tile [s][h], swizzled
  __shared__ __attribute__((aligned(16))) bf16 Vs[128 * 64];   // Vt tile [h][s], swizzled
  __shared__ __attribute__((aligned(16))) bf16 Ps[4][16 * 72]; // wave-private P

  for (int job = 0; job < 2; ++job) {
    const int tile = job ? p : (31 - p);
    const int t0 = tile * 64;

    // k fragments (A operand, 16 rows per wave) in registers
    bf16x8 af[4];
    {
      const bf16* kp = kb + ((size_t)b * TT + t0 + w * 16 + l15) * HH + l4 * 8;
#pragma unroll
      for (int kc = 0; kc < 4; ++kc) af[kc] = *(const bf16x8*)(kp + kc * 32);
    }

    f32x4 o[8];
#pragma unroll
    for (int j = 0; j < 8; ++j) o[j] = f32x4{0.f, 0.f, 0.f, 0.f};
    float mrow[4], lrow[4];
#pragma unroll
    for (int e = 0; e < 4; ++e) { mrow[e] = -1e30f; lrow[e] = 0.f; }

    const int nst = tile + 1;
    for (int jt = 0; jt < nst; ++jt) {
      const int s0 = jt * 64;
      {
        const bf16* Eg = qb + ((size_t)b * TT + s0) * HH;      // [64][128]
#pragma unroll
        for (int it = 0; it < 4; ++it) {
          int L = w * 256 + it * 64 + lane;                    // chunk id
          int er = L >> 4, ec = L & 15;
          int ecs = ec ^ (er & 7);
          gl_lds16(Eg + er * HH + ecs * 8, Es + (size_t)(w * 256 + it * 64) * 8);
        }
        const bf16* Vg = Vt + (size_t)b * HH * TT + s0;        // rows h, 64 cols
#pragma unroll
        for (int it = 0; it < 4; ++it) {
          int L = w * 256 + it * 64 + lane;
          int vr = L >> 3, vc = L & 7;
          int vcs = vc ^ (vr & 7);
          gl_lds16(Vg + (size_t)vr * TT + vcs * 8, Vs + (size_t)(w * 256 + it * 64) * 8);
        }
      }
      __syncthreads();

      // S = k . q^T   (already in exp2/log2 domain via pre-scaled k)
      f32x4 s[4];
#pragma unroll
      for (int j = 0; j < 4; ++j) s[j] = f32x4{0.f, 0.f, 0.f, 0.f};
#pragma unroll
      for (int kc = 0; kc < 4; ++kc) {
        bf16x8 ef[4];
#pragma unroll
        for (int fn = 0; fn < 4; ++fn) {
          int er = fn * 16 + l15;
          int c = kc * 4 + l4;
          int cs = c ^ (er & 7);
          ef[fn] = *(const bf16x8*)&Es[er * 128 + cs * 8];
        }
#pragma unroll
        for (int fn = 0; fn < 4; ++fn)
          s[fn] = __builtin_amdgcn_mfma_f32_16x16x32_bf16(af[kc], ef[fn],
                                                          s[fn], 0, 0, 0);
      }

      // causal mask (s_glob > t_glob -> -inf)
      if (s0 + 63 > t0 + w * 16) {
#pragma unroll
        for (int fn = 0; fn < 4; ++fn)
#pragma unroll
          for (int e = 0; e < 4; ++e) {
            int tg = t0 + w * 16 + l4 * 4 + e;
            int sg = s0 + fn * 16 + l15;
            if (sg > tg) s[fn][e] = -1e30f;
          }
      }

      // online softmax (log2 domain), defer-max rescale (threshold 8)
      float mx[4];
#pragma unroll
      for (int e = 0; e < 4; ++e) {
        float m = fmaxf(fmaxf(s[0][e], s[1][e]), fmaxf(s[2][e], s[3][e]));
#pragma unroll
        for (int d = 1; d < 16; d <<= 1) m = fmaxf(m, __shfl_xor(m, d));
        mx[e] = m;
      }
      float g = fmaxf(fmaxf(mx[0] - mrow[0], mx[1] - mrow[1]),
                      fmaxf(mx[2] - mrow[2], mx[3] - mrow[3]));
      if (!__all(g <= 8.0f)) {
#pragma unroll
        for (int e = 0; e < 4; ++e) {
          float mn = fmaxf(mrow[e], mx[e]);
          float rsc = exp2f(mrow[e] - mn);
          lrow[e] *= rsc;
#pragma unroll
          for (int fh = 0; fh < 8; ++fh) o[fh][e] *= rsc;
          mrow[e] = mn;
        }
      }
#pragma unroll
      for (int e = 0; e < 4; ++e) {
        float ps = 0.f;
#pragma unroll
        for (int fn = 0; fn < 4; ++fn) {
          float pv = exp2f(s[fn][e] - mrow[e]);
          s[fn][e] = pv;
          ps += pv;
        }
#pragma unroll
        for (int d = 1; d < 16; d <<= 1) ps += __shfl_xor(ps, d);
        lrow[e] += ps;
      }

      // P -> wave-private LDS (bf16), then PV MFMA
#pragma unroll
      for (int fn = 0; fn < 4; ++fn)
#pragma unroll
        for (int e = 0; e < 4; ++e)
          Ps[w][(l4 * 4 + e) * 72 + fn * 16 + l15] = (bf16)s[fn][e];

#pragma unroll
      for (int kc = 0; kc < 2; ++kc) {
        bf16x8 pf = *(const bf16x8*)&Ps[w][l15 * 72 + kc * 32 + l4 * 8];
#pragma unroll
        for (int fh = 0; fh < 8; ++fh) {
          int vr = fh * 16 + l15;
          int c = kc * 4 + l4;
          int cs = c ^ (vr & 7);
          bf16x8 vf = *(const bf16x8*)&Vs[vr * 64 + cs * 8];
          o[fh] = __builtin_amdgcn_mfma_f32_16x16x32_bf16(pf, vf, o[fh], 0, 0, 0);
        }
      }
      __syncthreads();
    }

    // epilogue: O / l -> fp32 out
#pragma unroll
    for (int e = 0; e < 4; ++e) {
      float rl = 1.0f / lrow[e];
      int tg = t0 + w * 16 + l4 * 4 + e;
#pragma unroll
      for (int fh = 0; fh < 8; ++fh)
        out[((size_t)b * TT + tg) * HH + fh * 16 + l15] = o[fh][e] * rl;
    }
  }
}

extern "C" void kernel_launch(void* const* d_in, const int* in_sizes, int n_in,
                              void* d_out, int out_size, void* d_ws, size_t ws_size,
                              hipStream_t stream) {
  (void)in_sizes; (void)n_in; (void)out_size; (void)ws_size;
  const float* x  = (const float*)d_in[0];
  const float* Wk = (const float*)d_in[1];
  const float* bk = (const float*)d_in[2];
  const float* Wq = (const float*)d_in[3];
  const float* bq = (const float*)d_in[4];
  const float* Wv = (const float*)d_in[5];
  const float* bv = (const float*)d_in[6];
  float* out = (float*)d_out;

  const size_t NTH = (size_t)BB * TT * HH;   // 8388608
  bf16* kb = (bf16*)d_ws;
  bf16* qb = kb + NTH;
  bf16* Vt = qb + NTH;
  bf16* Wt = Vt + NTH;                        // 3*128*1024 bf16
  float* bcat = (float*)(Wt + (size_t)3 * HH * DD);

  prep_w<<<192, 256, 0, stream>>>(Wk, Wq, Wv, bk, bq, bv, Wt, bcat);
  qkv_proj<<<1024, 256, 0, stream>>>(x, Wt, bcat, kb, qb, Vt);
  attn<<<512, 256, 0, stream>>>(kb, qb, Vt, out);
}

// Round 4
// 231.125 us; speedup vs baseline: 1.1003x; 1.1003x over previous
//
#include <hip/hip_runtime.h>
#include <hip/hip_bf16.h>
#include <stdint.h>

typedef __bf16 bf16;
typedef __bf16 bf16x8 __attribute__((ext_vector_type(8)));
typedef __bf16 bf16x4 __attribute__((ext_vector_type(4)));
typedef float f32x4 __attribute__((ext_vector_type(4)));
typedef float f32x8 __attribute__((ext_vector_type(8)));

#define BB 32
#define TT 2048
#define DD 1024
#define HH 128
#define SCALE 0.08838834764831845f   // H^-0.5
#define LOG2E 1.4426950408889634f
#define KS (SCALE * LOG2E)

__device__ __forceinline__ void gl_lds16(const bf16* g, bf16* l) {
  __builtin_amdgcn_global_load_lds((__attribute__((address_space(1))) const void*)g,
                                   (__attribute__((address_space(3))) void*)l,
                                   16, 0, 0);
}

// ---------------- kernel 0: Wt[mat][h][d] = W[d][h] (fp32 -> bf16) -------------
// mat 0 (Wk) pre-scaled by SCALE*LOG2E so softmax runs in exp2 domain with no
// extra multiplies. Also emits concatenated fp32 bias bcat[384] (bk scaled).
__global__ __launch_bounds__(256) void prep_w(const float* __restrict__ Wk,
                                              const float* __restrict__ Wq,
                                              const float* __restrict__ Wv,
                                              const float* __restrict__ bk,
                                              const float* __restrict__ bq,
                                              const float* __restrict__ bv,
                                              bf16* __restrict__ Wt,
                                              float* __restrict__ bcat) {
  int tid = blockIdx.x * 256 + threadIdx.x;   // 0..49151
  if (tid < 384) {
    int mat = tid >> 7, h = tid & 127;
    float bb = (mat == 0) ? bk[h] : (mat == 1) ? bq[h] : bv[h];
    bcat[tid] = (mat == 0) ? bb * KS : bb;
  }
  int mat = tid >> 14;
  int r = tid & 16383;
  int h = r & 127;
  int d0 = (r >> 7) << 3;
  const float* W = (mat == 0) ? Wk : (mat == 1) ? Wq : Wv;
  const float ks = (mat == 0) ? KS : 1.0f;
  bf16x8 v;
#pragma unroll
  for (int i = 0; i < 8; ++i) v[i] = (bf16)(W[(size_t)(d0 + i) * HH + h] * ks);
  *(bf16x8*)(Wt + ((size_t)mat * HH + h) * DD + d0) = v;
}

// ---------------- kernel 1: fused QKV projection GEMM (bf16 MFMA) --------------
// ONE pass over x: block = 64 rows x 384 cols (cols = [k|q|v]), 1024 blocks.
// A (x) staged in LDS (bf16, XOR-swizzled, double-buffered, BK=64).
// B (Wt) read from global (L2-resident) through a REGISTER double-buffer,
// prefetched one kc-chunk (K=32) ahead so L2 latency hides under 24 MFMAs.
// 4 waves, wave tile 64x96 (4 m-frags x 6 n-frags).
__global__ __launch_bounds__(256, 2) void qkv_proj(
    const float* __restrict__ x, const bf16* __restrict__ Wt,
    const float* __restrict__ bcat,
    bf16* __restrict__ kb, bf16* __restrict__ qb, bf16* __restrict__ Vt) {
  const int bid = blockIdx.x;
  const int tid = threadIdx.x;
  const int lane = tid & 63;
  const int w = tid >> 6;                    // wave id = N-tile
  const int l15 = lane & 15, l4 = lane >> 4;
  const size_t row0 = (size_t)bid * 64;
  const int colbase = w * 96;

  __shared__ __attribute__((aligned(16))) bf16 As[2][64][64];

  // staging coords: 2 iters x 256 threads = 512 chunks = 64 rows x 8 chunks
  const int sr0 = tid >> 3, sc0 = tid & 7;           // iter 0
  const int sr1 = (256 + tid) >> 3, sc1 = tid & 7;   // iter 1

  f32x4 acc[4][6];
#pragma unroll
  for (int m = 0; m < 4; ++m)
#pragma unroll
    for (int n = 0; n < 6; ++n) acc[m][n] = f32x4{0.f, 0.f, 0.f, 0.f};

  auto cvt_store = [&](int buf, f32x8 a, int r, int c) {
    bf16x8 t;
#pragma unroll
    for (int i = 0; i < 8; ++i) t[i] = (bf16)a[i];
    *(bf16x8*)&As[buf][r][(c ^ (r & 7)) * 8] = t;
  };

  // W fragment base: frag n at +n*16*DD, k-chunk at +koff
  const bf16* Wp = Wt + (size_t)(colbase + l15) * DD + l4 * 8;
  bf16x8 bfr[2][6];

  // prologue: prefetch W chunk 0 into buf 0; stage x step 0 into LDS buf 0
#pragma unroll
  for (int n = 0; n < 6; ++n)
    bfr[0][n] = *(const bf16x8*)(Wp + (size_t)n * 16 * DD);
  {
    f32x8 a0 = *(const f32x8*)(x + (row0 + sr0) * DD + sc0 * 8);
    f32x8 a1 = *(const f32x8*)(x + (row0 + sr1) * DD + sc1 * 8);
    cvt_store(0, a0, sr0, sc0);
    cvt_store(0, a1, sr1, sc1);
  }
  __syncthreads();

  for (int step = 0; step < 16; ++step) {
    const int k0 = step * 64;
    const int cur = step & 1;

    // issue next-tile x loads early (consumed after the MFMA block)
    f32x8 n0, n1;
    if (step < 15) {
      n0 = *(const f32x8*)(x + (row0 + sr0) * DD + k0 + 64 + sc0 * 8);
      n1 = *(const f32x8*)(x + (row0 + sr1) * DD + k0 + 64 + sc1 * 8);
    }

#pragma unroll
    for (int kc = 0; kc < 2; ++kc) {
      // prefetch NEXT kc-chunk's W frags into the other buffer
      const int koff = k0 + kc * 32 + 32;
      if (koff < DD) {
#pragma unroll
        for (int n = 0; n < 6; ++n)
          bfr[kc ^ 1][n] = *(const bf16x8*)(Wp + (size_t)n * 16 * DD + koff);
      }
      bf16x8 af[4];
#pragma unroll
      for (int m = 0; m < 4; ++m) {
        int r = m * 16 + l15;
        af[m] = *(const bf16x8*)&As[cur][r][((kc * 4 + l4) ^ (r & 7)) * 8];
      }
#pragma unroll
      for (int m = 0; m < 4; ++m)
#pragma unroll
        for (int n = 0; n < 6; ++n)
          acc[m][n] = __builtin_amdgcn_mfma_f32_16x16x32_bf16(af[m], bfr[kc][n],
                                                              acc[m][n], 0, 0, 0);
    }

    if (step < 15) {
      cvt_store(cur ^ 1, n0, sr0, sc0);
      cvt_store(cur ^ 1, n1, sr1, sc1);
    }
    __syncthreads();
  }

  // epilogue
  float bvv[6];
#pragma unroll
  for (int n = 0; n < 6; ++n) bvv[n] = bcat[colbase + n * 16 + l15];

  const int bidx = bid >> 5;
  const int tloc0 = (bid & 31) * 64;
#pragma unroll
  for (int m = 0; m < 4; ++m)
#pragma unroll
    for (int n = 0; n < 6; ++n) {
      int col = colbase + n * 16 + l15;
      int mat = col >> 7;
      int hcol = col & 127;
      if (mat == 2) {
        bf16x4 v4;
#pragma unroll
        for (int e = 0; e < 4; ++e) v4[e] = (bf16)(acc[m][n][e] + bvv[n]);
        int t = tloc0 + m * 16 + l4 * 4;
        *(bf16x4*)(Vt + ((size_t)bidx * HH + hcol) * TT + t) = v4;
      } else {
        bf16* dst = (mat == 0) ? kb : qb;
#pragma unroll
        for (int e = 0; e < 4; ++e) {
          size_t rowg = row0 + m * 16 + l4 * 4 + e;
          dst[rowg * HH + hcol] = (bf16)(acc[m][n][e] + bvv[n]);
        }
      }
    }
}

// ---------------- kernel 2: fused causal flash attention -----------------------
// quirk: scores[t][s] = k[t].q[s] -> k rows are the softmax rows (k pre-scaled
// by SCALE*LOG2E, so softmax is computed with exp2 directly).
// grid 512; block 256 = 4 waves * 16 rows = 64-row t-tile.
// Each block runs TWO complementary jobs: tiles (31-p) and (p) -> exactly
// 33 s-iterations per block (perfect balance), all 512 blocks co-resident.
__global__ __launch_bounds__(256, 3) void attn(const bf16* __restrict__ kb,
                                               const bf16* __restrict__ qb,
                                               const bf16* __restrict__ Vt,
                                               float* __restrict__ out) {
  const int bid = blockIdx.x;
  const int b = bid & 31;
  const int p = bid >> 5;                 // 0..15
  const int tid = threadIdx.x;
  const int lane = tid & 63;
  const int w = tid >> 6;
  const int l15 = lane & 15, l4 = lane >> 4;

  __shared__ __attribute__((aligned(16))) bf16 Es[64 * 128];   // q tile [s][h], swizzled
  __shared__ __attribute__((aligned(16))) bf16 Vs[128 * 64];   // Vt tile [h][s], swizzled
  __shared__ __attribute__((aligned(16))) bf16 Ps[4][16 * 72]; // wave-private P

  for (int job = 0; job < 2; ++job) {
    const int tile = job ? p : (31 - p);
    const int t0 = tile * 64;

    // k fragments (A operand, 16 rows per wave) in registers
    bf16x8 af[4];
    {
      const bf16* kp = kb + ((size_t)b * TT + t0 + w * 16 + l15) * HH + l4 * 8;
#pragma unroll
      for (int kc = 0; kc < 4; ++kc) af[kc] = *(const bf16x8*)(kp + kc * 32);
    }

    f32x4 o[8];
#pragma unroll
    for (int j = 0; j < 8; ++j) o[j] = f32x4{0.f, 0.f, 0.f, 0.f};
    float mrow[4], lrow[4];
#pragma unroll
    for (int e = 0; e < 4; ++e) { mrow[e] = -1e30f; lrow[e] = 0.f; }

    const int nst = tile + 1;
    for (int jt = 0; jt < nst; ++jt) {
      const int s0 = jt * 64;
      {
        const bf16* Eg = qb + ((size_t)b * TT + s0) * HH;      // [64][128]
#pragma unroll
        for (int it = 0; it < 4; ++it) {
          int L = w * 256 + it * 64 + lane;                    // chunk id
          int er = L >> 4, ec = L & 15;
          int ecs = ec ^ (er & 7);
          gl_lds16(Eg + er * HH + ecs * 8, Es + (size_t)(w * 256 + it * 64) * 8);
        }
        const bf16* Vg = Vt + (size_t)b * HH * TT + s0;        // rows h, 64 cols
#pragma unroll
        for (int it = 0; it < 4; ++it) {
          int L = w * 256 + it * 64 + lane;
          int vr = L >> 3, vc = L & 7;
          int vcs = vc ^ (vr & 7);
          gl_lds16(Vg + (size_t)vr * TT + vcs * 8, Vs + (size_t)(w * 256 + it * 64) * 8);
        }
      }
      __syncthreads();

      // S = k . q^T   (already in exp2/log2 domain via pre-scaled k)
      f32x4 s[4];
#pragma unroll
      for (int j = 0; j < 4; ++j) s[j] = f32x4{0.f, 0.f, 0.f, 0.f};
#pragma unroll
      for (int kc = 0; kc < 4; ++kc) {
        bf16x8 ef[4];
#pragma unroll
        for (int fn = 0; fn < 4; ++fn) {
          int er = fn * 16 + l15;
          int c = kc * 4 + l4;
          int cs = c ^ (er & 7);
          ef[fn] = *(const bf16x8*)&Es[er * 128 + cs * 8];
        }
#pragma unroll
        for (int fn = 0; fn < 4; ++fn)
          s[fn] = __builtin_amdgcn_mfma_f32_16x16x32_bf16(af[kc], ef[fn],
                                                          s[fn], 0, 0, 0);
      }

      // causal mask (s_glob > t_glob -> -inf)
      if (s0 + 63 > t0 + w * 16) {
#pragma unroll
        for (int fn = 0; fn < 4; ++fn)
#pragma unroll
          for (int e = 0; e < 4; ++e) {
            int tg = t0 + w * 16 + l4 * 4 + e;
            int sg = s0 + fn * 16 + l15;
            if (sg > tg) s[fn][e] = -1e30f;
          }
      }

      // online softmax (log2 domain), defer-max rescale (threshold 8)
      float mx[4];
#pragma unroll
      for (int e = 0; e < 4; ++e) {
        float m = fmaxf(fmaxf(s[0][e], s[1][e]), fmaxf(s[2][e], s[3][e]));
#pragma unroll
        for (int d = 1; d < 16; d <<= 1) m = fmaxf(m, __shfl_xor(m, d));
        mx[e] = m;
      }
      float g = fmaxf(fmaxf(mx[0] - mrow[0], mx[1] - mrow[1]),
                      fmaxf(mx[2] - mrow[2], mx[3] - mrow[3]));
      if (!__all(g <= 8.0f)) {
#pragma unroll
        for (int e = 0; e < 4; ++e) {
          float mn = fmaxf(mrow[e], mx[e]);
          float rsc = exp2f(mrow[e] - mn);
          lrow[e] *= rsc;
#pragma unroll
          for (int fh = 0; fh < 8; ++fh) o[fh][e] *= rsc;
          mrow[e] = mn;
        }
      }
#pragma unroll
      for (int e = 0; e < 4; ++e) {
        float ps = 0.f;
#pragma unroll
        for (int fn = 0; fn < 4; ++fn) {
          float pv = exp2f(s[fn][e] - mrow[e]);
          s[fn][e] = pv;
          ps += pv;
        }
#pragma unroll
        for (int d = 1; d < 16; d <<= 1) ps += __shfl_xor(ps, d);
        lrow[e] += ps;
      }

      // P -> wave-private LDS (bf16), then PV MFMA
#pragma unroll
      for (int fn = 0; fn < 4; ++fn)
#pragma unroll
        for (int e = 0; e < 4; ++e)
          Ps[w][(l4 * 4 + e) * 72 + fn * 16 + l15] = (bf16)s[fn][e];

#pragma unroll
      for (int kc = 0; kc < 2; ++kc) {
        bf16x8 pf = *(const bf16x8*)&Ps[w][l15 * 72 + kc * 32 + l4 * 8];
#pragma unroll
        for (int fh = 0; fh < 8; ++fh) {
          int vr = fh * 16 + l15;
          int c = kc * 4 + l4;
          int cs = c ^ (vr & 7);
          bf16x8 vf = *(const bf16x8*)&Vs[vr * 64 + cs * 8];
          o[fh] = __builtin_amdgcn_mfma_f32_16x16x32_bf16(pf, vf, o[fh], 0, 0, 0);
        }
      }
      __syncthreads();
    }

    // epilogue: O / l -> fp32 out
#pragma unroll
    for (int e = 0; e < 4; ++e) {
      float rl = 1.0f / lrow[e];
      int tg = t0 + w * 16 + l4 * 4 + e;
#pragma unroll
      for (int fh = 0; fh < 8; ++fh)
        out[((size_t)b * TT + tg) * HH + fh * 16 + l15] = o[fh][e] * rl;
    }
  }
}

extern "C" void kernel_launch(void* const* d_in, const int* in_sizes, int n_in,
                              void* d_out, int out_size, void* d_ws, size_t ws_size,
                              hipStream_t stream) {
  (void)in_sizes; (void)n_in; (void)out_size; (void)ws_size;
  const float* x  = (const float*)d_in[0];
  const float* Wk = (const float*)d_in[1];
  const float* bk = (const float*)d_in[2];
  const float* Wq = (const float*)d_in[3];
  const float* bq = (const float*)d_in[4];
  const float* Wv = (const float*)d_in[5];
  const float* bv = (const float*)d_in[6];
  float* out = (float*)d_out;

  const size_t NTH = (size_t)BB * TT * HH;   // 8388608
  bf16* kb = (bf16*)d_ws;
  bf16* qb = kb + NTH;
  bf16* Vt = qb + NTH;
  bf16* Wt = Vt + NTH;                        // 3*128*1024 bf16
  float* bcat = (float*)(Wt + (size_t)3 * HH * DD);

  prep_w<<<192, 256, 0, stream>>>(Wk, Wq, Wv, bk, bq, bv, Wt, bcat);
  qkv_proj<<<1024, 256, 0, stream>>>(x, Wt, bcat, kb, qb, Vt);
  attn<<<512, 256, 0, stream>>>(kb, qb, Vt, out);
}

// Round 5
// 213.783 us; speedup vs baseline: 1.1895x; 1.0811x over previous
//
#include <hip/hip_runtime.h>
#include <hip/hip_bf16.h>
#include <stdint.h>

typedef __bf16 bf16;
typedef __bf16 bf16x8 __attribute__((ext_vector_type(8)));
typedef __bf16 bf16x4 __attribute__((ext_vector_type(4)));
typedef float f32x4 __attribute__((ext_vector_type(4)));
typedef float f32x8 __attribute__((ext_vector_type(8)));

#define BB 32
#define TT 2048
#define DD 1024
#define HH 128
#define SCALE 0.08838834764831845f   // H^-0.5
#define LOG2E 1.4426950408889634f
#define KS (SCALE * LOG2E)

__device__ __forceinline__ void gl_lds16(const bf16* g, bf16* l) {
  __builtin_amdgcn_global_load_lds((__attribute__((address_space(1))) const void*)g,
                                   (__attribute__((address_space(3))) void*)l,
                                   16, 0, 0);
}
__device__ __forceinline__ void gl_lds16f(const float* g, float* l) {
  __builtin_amdgcn_global_load_lds((__attribute__((address_space(1))) const void*)g,
                                   (__attribute__((address_space(3))) void*)l,
                                   16, 0, 0);
}

// ---------------- kernel 0: Wt[mat][h][d] = W[d][h] (fp32 -> bf16) -------------
// mat 0 (Wk) pre-scaled by SCALE*LOG2E so softmax runs in exp2 domain with no
// extra multiplies. Also emits concatenated fp32 bias bcat[384] (bk scaled).
__global__ __launch_bounds__(256) void prep_w(const float* __restrict__ Wk,
                                              const float* __restrict__ Wq,
                                              const float* __restrict__ Wv,
                                              const float* __restrict__ bk,
                                              const float* __restrict__ bq,
                                              const float* __restrict__ bv,
                                              bf16* __restrict__ Wt,
                                              float* __restrict__ bcat) {
  int tid = blockIdx.x * 256 + threadIdx.x;   // 0..49151
  if (tid < 384) {
    int mat = tid >> 7, h = tid & 127;
    float bb = (mat == 0) ? bk[h] : (mat == 1) ? bq[h] : bv[h];
    bcat[tid] = (mat == 0) ? bb * KS : bb;
  }
  int mat = tid >> 14;
  int r = tid & 16383;
  int h = r & 127;
  int d0 = (r >> 7) << 3;
  const float* W = (mat == 0) ? Wk : (mat == 1) ? Wq : Wv;
  const float ks = (mat == 0) ? KS : 1.0f;
  bf16x8 v;
#pragma unroll
  for (int i = 0; i < 8; ++i) v[i] = (bf16)(W[(size_t)(d0 + i) * HH + h] * ks);
  *(bf16x8*)(Wt + ((size_t)mat * HH + h) * DD + d0) = v;
}

// ---------------- kernel 1: fused QKV projection GEMM (bf16 MFMA) --------------
// ONE pass over x: block = 64 rows x 384 cols (cols = [k|q|v]), 1024 blocks.
// BOTH operands staged via global_load_lds (x as fp32, W as bf16), BK=32,
// double-buffered: the wave compute path has ZERO vmem waits (all lgkm), so
// staging loads stay in flight for ~the whole step (no vmcnt FIFO poisoning).
// Both LDS layouts XOR-swizzled via pre-swizzled global source (rule 21).
// 4 waves, wave tile 64x96 (4 m-frags x 6 n-frags).
__global__ __launch_bounds__(256, 2) void qkv_proj(
    const float* __restrict__ x, const bf16* __restrict__ Wt,
    const float* __restrict__ bcat,
    bf16* __restrict__ kb, bf16* __restrict__ qb, bf16* __restrict__ Vt) {
  const int bid = blockIdx.x;
  const int tid = threadIdx.x;
  const int lane = tid & 63;
  const int w = tid >> 6;                    // wave id = N-tile
  const int l15 = lane & 15, l4 = lane >> 4;
  const size_t row0 = (size_t)bid * 64;
  const int colbase = w * 96;

  __shared__ __attribute__((aligned(16))) float As[2][64][32];   // 16 KB
  __shared__ __attribute__((aligned(16))) bf16  Ws[2][384][32];  // 48 KB

  f32x4 acc[4][6];
#pragma unroll
  for (int m = 0; m < 4; ++m)
#pragma unroll
    for (int n = 0; n < 6; ++n) acc[m][n] = f32x4{0.f, 0.f, 0.f, 0.f};

  // stage k-slice [k0, k0+32) into buf: x 512 chunks (16B), W 1536 chunks
  auto stage = [&](int buf, int k0) {
#pragma unroll
    for (int i = 0; i < 2; ++i) {
      int base = i * 256 + w * 64;              // wave-uniform
      int L = base + lane;
      int r = L >> 3, c = L & 7;                // LDS slot (r, c) of 8/row
      const float* src = x + (row0 + r) * DD + k0 + ((c ^ (r & 7)) << 2);
      gl_lds16f(src, &As[buf][0][0] + (size_t)base * 4);
    }
#pragma unroll
    for (int i = 0; i < 6; ++i) {
      int base = i * 256 + w * 64;
      int L = base + lane;
      int col = L >> 2, j = L & 3;              // LDS slot (col, j) of 4/row
      const bf16* src = Wt + (size_t)col * DD + k0 + ((j ^ ((col >> 1) & 3)) << 3);
      gl_lds16(src, &Ws[buf][0][0] + (size_t)base * 8);
    }
  };

  stage(0, 0);
  __syncthreads();

  for (int step = 0; step < 32; ++step) {
    const int cur = step & 1;
    if (step + 1 < 32) stage(cur ^ 1, (step + 1) * 32);

    // af: fp32 from LDS -> bf16 fragments (swizzled 16B chunks)
    bf16x8 af[4];
#pragma unroll
    for (int m = 0; m < 4; ++m) {
      int r = m * 16 + l15;
      int c0 = (2 * l4) ^ (r & 7), c1 = (2 * l4 + 1) ^ (r & 7);
      f32x4 lo = *(const f32x4*)&As[cur][r][c0 * 4];
      f32x4 hi = *(const f32x4*)&As[cur][r][c1 * 4];
#pragma unroll
      for (int i = 0; i < 4; ++i) { af[m][i] = (bf16)lo[i]; af[m][4 + i] = (bf16)hi[i]; }
    }
    bf16x8 bfr[6];
#pragma unroll
    for (int n = 0; n < 6; ++n) {
      int col = colbase + n * 16 + l15;
      bfr[n] = *(const bf16x8*)&Ws[cur][col][(l4 ^ ((col >> 1) & 3)) * 8];
    }
#pragma unroll
    for (int m = 0; m < 4; ++m)
#pragma unroll
      for (int n = 0; n < 6; ++n)
        acc[m][n] = __builtin_amdgcn_mfma_f32_16x16x32_bf16(af[m], bfr[n],
                                                            acc[m][n], 0, 0, 0);
    __syncthreads();
  }

  // epilogue
  float bvv[6];
#pragma unroll
  for (int n = 0; n < 6; ++n) bvv[n] = bcat[colbase + n * 16 + l15];

  const int bidx = bid >> 5;
  const int tloc0 = (bid & 31) * 64;
#pragma unroll
  for (int m = 0; m < 4; ++m)
#pragma unroll
    for (int n = 0; n < 6; ++n) {
      int col = colbase + n * 16 + l15;
      int mat = col >> 7;
      int hcol = col & 127;
      if (mat == 2) {
        bf16x4 v4;
#pragma unroll
        for (int e = 0; e < 4; ++e) v4[e] = (bf16)(acc[m][n][e] + bvv[n]);
        int t = tloc0 + m * 16 + l4 * 4;
        *(bf16x4*)(Vt + ((size_t)bidx * HH + hcol) * TT + t) = v4;
      } else {
        bf16* dst = (mat == 0) ? kb : qb;
#pragma unroll
        for (int e = 0; e < 4; ++e) {
          size_t rowg = row0 + m * 16 + l4 * 4 + e;
          dst[rowg * HH + hcol] = (bf16)(acc[m][n][e] + bvv[n]);
        }
      }
    }
}

// ---------------- kernel 2: fused causal flash attention -----------------------
// quirk: scores[t][s] = k[t].q[s] -> k rows are the softmax rows (k pre-scaled
// by SCALE*LOG2E, so softmax is computed with exp2 directly).
// grid 512; block 256 = 4 waves * 16 rows = 64-row t-tile.
// Each block runs TWO complementary jobs: tiles (31-p) and (p) -> exactly
// 33 s-iterations per block (perfect balance), all 512 blocks co-resident.
__global__ __launch_bounds__(256, 3) void attn(const bf16* __restrict__ kb,
                                               const bf16* __restrict__ qb,
                                               const bf16* __restrict__ Vt,
                                               float* __restrict__ out) {
  const int bid = blockIdx.x;
  const int b = bid & 31;
  const int p = bid >> 5;                 // 0..15
  const int tid = threadIdx.x;
  const int lane = tid & 63;
  const int w = tid >> 6;
  const int l15 = lane & 15, l4 = lane >> 4;

  __shared__ __attribute__((aligned(16))) bf16 Es[64 * 128];   // q tile [s][h], swizzled
  __shared__ __attribute__((aligned(16))) bf16 Vs[128 * 64];   // Vt tile [h][s], swizzled
  __shared__ __attribute__((aligned(16))) bf16 Ps[4][16 * 72]; // wave-private P

  for (int job = 0; job < 2; ++job) {
    const int tile = job ? p : (31 - p);
    const int t0 = tile * 64;

    // k fragments (A operand, 16 rows per wave) in registers
    bf16x8 af[4];
    {
      const bf16* kp = kb + ((size_t)b * TT + t0 + w * 16 + l15) * HH + l4 * 8;
#pragma unroll
      for (int kc = 0; kc < 4; ++kc) af[kc] = *(const bf16x8*)(kp + kc * 32);
    }

    f32x4 o[8];
#pragma unroll
    for (int j = 0; j < 8; ++j) o[j] = f32x4{0.f, 0.f, 0.f, 0.f};
    float mrow[4], lrow[4];
#pragma unroll
    for (int e = 0; e < 4; ++e) { mrow[e] = -1e30f; lrow[e] = 0.f; }

    const int nst = tile + 1;
    for (int jt = 0; jt < nst; ++jt) {
      const int s0 = jt * 64;
      {
        const bf16* Eg = qb + ((size_t)b * TT + s0) * HH;      // [64][128]
#pragma unroll
        for (int it = 0; it < 4; ++it) {
          int L = w * 256 + it * 64 + lane;                    // chunk id
          int er = L >> 4, ec = L & 15;
          int ecs = ec ^ (er & 7);
          gl_lds16(Eg + er * HH + ecs * 8, Es + (size_t)(w * 256 + it * 64) * 8);
        }
        const bf16* Vg = Vt + (size_t)b * HH * TT + s0;        // rows h, 64 cols
#pragma unroll
        for (int it = 0; it < 4; ++it) {
          int L = w * 256 + it * 64 + lane;
          int vr = L >> 3, vc = L & 7;
          int vcs = vc ^ (vr & 7);
          gl_lds16(Vg + (size_t)vr * TT + vcs * 8, Vs + (size_t)(w * 256 + it * 64) * 8);
        }
      }
      __syncthreads();

      // S = k . q^T   (already in exp2/log2 domain via pre-scaled k)
      f32x4 s[4];
#pragma unroll
      for (int j = 0; j < 4; ++j) s[j] = f32x4{0.f, 0.f, 0.f, 0.f};
#pragma unroll
      for (int kc = 0; kc < 4; ++kc) {
        bf16x8 ef[4];
#pragma unroll
        for (int fn = 0; fn < 4; ++fn) {
          int er = fn * 16 + l15;
          int c = kc * 4 + l4;
          int cs = c ^ (er & 7);
          ef[fn] = *(const bf16x8*)&Es[er * 128 + cs * 8];
        }
#pragma unroll
        for (int fn = 0; fn < 4; ++fn)
          s[fn] = __builtin_amdgcn_mfma_f32_16x16x32_bf16(af[kc], ef[fn],
                                                          s[fn], 0, 0, 0);
      }

      // causal mask (s_glob > t_glob -> -inf)
      if (s0 + 63 > t0 + w * 16) {
#pragma unroll
        for (int fn = 0; fn < 4; ++fn)
#pragma unroll
          for (int e = 0; e < 4; ++e) {
            int tg = t0 + w * 16 + l4 * 4 + e;
            int sg = s0 + fn * 16 + l15;
            if (sg > tg) s[fn][e] = -1e30f;
          }
      }

      // online softmax (log2 domain), defer-max rescale (threshold 8)
      float mx[4];
#pragma unroll
      for (int e = 0; e < 4; ++e) {
        float m = fmaxf(fmaxf(s[0][e], s[1][e]), fmaxf(s[2][e], s[3][e]));
#pragma unroll
        for (int d = 1; d < 16; d <<= 1) m = fmaxf(m, __shfl_xor(m, d));
        mx[e] = m;
      }
      float g = fmaxf(fmaxf(mx[0] - mrow[0], mx[1] - mrow[1]),
                      fmaxf(mx[2] - mrow[2], mx[3] - mrow[3]));
      if (!__all(g <= 8.0f)) {
#pragma unroll
        for (int e = 0; e < 4; ++e) {
          float mn = fmaxf(mrow[e], mx[e]);
          float rsc = exp2f(mrow[e] - mn);
          lrow[e] *= rsc;
#pragma unroll
          for (int fh = 0; fh < 8; ++fh) o[fh][e] *= rsc;
          mrow[e] = mn;
        }
      }
#pragma unroll
      for (int e = 0; e < 4; ++e) {
        float ps = 0.f;
#pragma unroll
        for (int fn = 0; fn < 4; ++fn) {
          float pv = exp2f(s[fn][e] - mrow[e]);
          s[fn][e] = pv;
          ps += pv;
        }
#pragma unroll
        for (int d = 1; d < 16; d <<= 1) ps += __shfl_xor(ps, d);
        lrow[e] += ps;
      }

      // P -> wave-private LDS (bf16), then PV MFMA
#pragma unroll
      for (int fn = 0; fn < 4; ++fn)
#pragma unroll
        for (int e = 0; e < 4; ++e)
          Ps[w][(l4 * 4 + e) * 72 + fn * 16 + l15] = (bf16)s[fn][e];

#pragma unroll
      for (int kc = 0; kc < 2; ++kc) {
        bf16x8 pf = *(const bf16x8*)&Ps[w][l15 * 72 + kc * 32 + l4 * 8];
#pragma unroll
        for (int fh = 0; fh < 8; ++fh) {
          int vr = fh * 16 + l15;
          int c = kc * 4 + l4;
          int cs = c ^ (vr & 7);
          bf16x8 vf = *(const bf16x8*)&Vs[vr * 64 + cs * 8];
          o[fh] = __builtin_amdgcn_mfma_f32_16x16x32_bf16(pf, vf, o[fh], 0, 0, 0);
        }
      }
      __syncthreads();
    }

    // epilogue: O / l -> fp32 out
#pragma unroll
    for (int e = 0; e < 4; ++e) {
      float rl = 1.0f / lrow[e];
      int tg = t0 + w * 16 + l4 * 4 + e;
#pragma unroll
      for (int fh = 0; fh < 8; ++fh)
        out[((size_t)b * TT + tg) * HH + fh * 16 + l15] = o[fh][e] * rl;
    }
  }
}

extern "C" void kernel_launch(void* const* d_in, const int* in_sizes, int n_in,
                              void* d_out, int out_size, void* d_ws, size_t ws_size,
                              hipStream_t stream) {
  (void)in_sizes; (void)n_in; (void)out_size; (void)ws_size;
  const float* x  = (const float*)d_in[0];
  const float* Wk = (const float*)d_in[1];
  const float* bk = (const float*)d_in[2];
  const float* Wq = (const float*)d_in[3];
  const float* bq = (const float*)d_in[4];
  const float* Wv = (const float*)d_in[5];
  const float* bv = (const float*)d_in[6];
  float* out = (float*)d_out;

  const size_t NTH = (size_t)BB * TT * HH;   // 8388608
  bf16* kb = (bf16*)d_ws;
  bf16* qb = kb + NTH;
  bf16* Vt = qb + NTH;
  bf16* Wt = Vt + NTH;                        // 3*128*1024 bf16
  float* bcat = (float*)(Wt + (size_t)3 * HH * DD);

  prep_w<<<192, 256, 0, stream>>>(Wk, Wq, Wv, bk, bq, bv, Wt, bcat);
  qkv_proj<<<1024, 256, 0, stream>>>(x, Wt, bcat, kb, qb, Vt);
  attn<<<512, 256, 0, stream>>>(kb, qb, Vt, out);
}

// Round 6
// 211.397 us; speedup vs baseline: 1.2030x; 1.0113x over previous
//
#include <hip/hip_runtime.h>
#include <hip/hip_bf16.h>
#include <stdint.h>

typedef __bf16 bf16;
typedef __bf16 bf16x8 __attribute__((ext_vector_type(8)));
typedef __bf16 bf16x4 __attribute__((ext_vector_type(4)));
typedef float f32x4 __attribute__((ext_vector_type(4)));
typedef float f32x8 __attribute__((ext_vector_type(8)));

#define BB 32
#define TT 2048
#define DD 1024
#define HH 128
#define SCALE 0.08838834764831845f   // H^-0.5
#define LOG2E 1.4426950408889634f
#define KS (SCALE * LOG2E)

__device__ __forceinline__ void gl_lds16(const bf16* g, bf16* l) {
  __builtin_amdgcn_global_load_lds((__attribute__((address_space(1))) const void*)g,
                                   (__attribute__((address_space(3))) void*)l,
                                   16, 0, 0);
}
// NT (non-temporal, CPol bit 1): evict-first — for zero-reuse x stream so it
// does not evict the L2-resident W panel.
__device__ __forceinline__ void gl_lds16f_nt(const float* g, float* l) {
  __builtin_amdgcn_global_load_lds((__attribute__((address_space(1))) const void*)g,
                                   (__attribute__((address_space(3))) void*)l,
                                   16, 0, 2);
}

// ---------------- kernel 0: Wt[mat][h][d] = W[d][h] (fp32 -> bf16) -------------
// mat 0 (Wk) pre-scaled by SCALE*LOG2E so softmax runs in exp2 domain with no
// extra multiplies. Also emits concatenated fp32 bias bcat[384] (bk scaled).
__global__ __launch_bounds__(256) void prep_w(const float* __restrict__ Wk,
                                              const float* __restrict__ Wq,
                                              const float* __restrict__ Wv,
                                              const float* __restrict__ bk,
                                              const float* __restrict__ bq,
                                              const float* __restrict__ bv,
                                              bf16* __restrict__ Wt,
                                              float* __restrict__ bcat) {
  int tid = blockIdx.x * 256 + threadIdx.x;   // 0..49151
  if (tid < 384) {
    int mat = tid >> 7, h = tid & 127;
    float bb = (mat == 0) ? bk[h] : (mat == 1) ? bq[h] : bv[h];
    bcat[tid] = (mat == 0) ? bb * KS : bb;
  }
  int mat = tid >> 14;
  int r = tid & 16383;
  int h = r & 127;
  int d0 = (r >> 7) << 3;
  const float* W = (mat == 0) ? Wk : (mat == 1) ? Wq : Wv;
  const float ks = (mat == 0) ? KS : 1.0f;
  bf16x8 v;
#pragma unroll
  for (int i = 0; i < 8; ++i) v[i] = (bf16)(W[(size_t)(d0 + i) * HH + h] * ks);
  *(bf16x8*)(Wt + ((size_t)mat * HH + h) * DD + d0) = v;
}

// ---------------- kernel 1: fused QKV projection GEMM (bf16 MFMA) --------------
// ONE pass over x: block = 64 rows x 384 cols (cols = [k|q|v]), 1024 blocks.
// BOTH operands staged via global_load_lds (x as fp32 NT-stream, W as bf16),
// BK=32, double-buffered: wave compute path has zero vmem waits.
// x loads are NON-TEMPORAL so the streaming x does not evict the W panel
// (768 KB, all blocks share it) from each XCD's L2.
// 4 waves, wave tile 64x96 (4 m-frags x 6 n-frags).
__global__ __launch_bounds__(256, 2) void qkv_proj(
    const float* __restrict__ x, const bf16* __restrict__ Wt,
    const float* __restrict__ bcat,
    bf16* __restrict__ kb, bf16* __restrict__ qb, bf16* __restrict__ Vt) {
  const int bid = blockIdx.x;
  const int tid = threadIdx.x;
  const int lane = tid & 63;
  const int w = tid >> 6;                    // wave id = N-tile
  const int l15 = lane & 15, l4 = lane >> 4;
  const size_t row0 = (size_t)bid * 64;
  const int colbase = w * 96;

  __shared__ __attribute__((aligned(16))) float As[2][64][32];   // 16 KB
  __shared__ __attribute__((aligned(16))) bf16  Ws[2][384][32];  // 48 KB

  f32x4 acc[4][6];
#pragma unroll
  for (int m = 0; m < 4; ++m)
#pragma unroll
    for (int n = 0; n < 6; ++n) acc[m][n] = f32x4{0.f, 0.f, 0.f, 0.f};

  // stage k-slice [k0, k0+32) into buf: x 512 chunks (16B), W 1536 chunks
  auto stage = [&](int buf, int k0) {
#pragma unroll
    for (int i = 0; i < 2; ++i) {
      int base = i * 256 + w * 64;              // wave-uniform
      int L = base + lane;
      int r = L >> 3, c = L & 7;                // LDS slot (r, c) of 8/row
      const float* src = x + (row0 + r) * DD + k0 + ((c ^ (r & 7)) << 2);
      gl_lds16f_nt(src, &As[buf][0][0] + (size_t)base * 4);
    }
#pragma unroll
    for (int i = 0; i < 6; ++i) {
      int base = i * 256 + w * 64;
      int L = base + lane;
      int col = L >> 2, j = L & 3;              // LDS slot (col, j) of 4/row
      const bf16* src = Wt + (size_t)col * DD + k0 + ((j ^ ((col >> 1) & 3)) << 3);
      gl_lds16(src, &Ws[buf][0][0] + (size_t)base * 8);
    }
  };

  stage(0, 0);
  __syncthreads();

  for (int step = 0; step < 32; ++step) {
    const int cur = step & 1;
    if (step + 1 < 32) stage(cur ^ 1, (step + 1) * 32);

    // af: fp32 from LDS -> bf16 fragments (swizzled 16B chunks)
    bf16x8 af[4];
#pragma unroll
    for (int m = 0; m < 4; ++m) {
      int r = m * 16 + l15;
      int c0 = (2 * l4) ^ (r & 7), c1 = (2 * l4 + 1) ^ (r & 7);
      f32x4 lo = *(const f32x4*)&As[cur][r][c0 * 4];
      f32x4 hi = *(const f32x4*)&As[cur][r][c1 * 4];
#pragma unroll
      for (int i = 0; i < 4; ++i) { af[m][i] = (bf16)lo[i]; af[m][4 + i] = (bf16)hi[i]; }
    }
    bf16x8 bfr[6];
#pragma unroll
    for (int n = 0; n < 6; ++n) {
      int col = colbase + n * 16 + l15;
      bfr[n] = *(const bf16x8*)&Ws[cur][col][(l4 ^ ((col >> 1) & 3)) * 8];
    }
#pragma unroll
    for (int m = 0; m < 4; ++m)
#pragma unroll
      for (int n = 0; n < 6; ++n)
        acc[m][n] = __builtin_amdgcn_mfma_f32_16x16x32_bf16(af[m], bfr[n],
                                                            acc[m][n], 0, 0, 0);
    __syncthreads();
  }

  // epilogue
  float bvv[6];
#pragma unroll
  for (int n = 0; n < 6; ++n) bvv[n] = bcat[colbase + n * 16 + l15];

  const int bidx = bid >> 5;
  const int tloc0 = (bid & 31) * 64;
#pragma unroll
  for (int m = 0; m < 4; ++m)
#pragma unroll
    for (int n = 0; n < 6; ++n) {
      int col = colbase + n * 16 + l15;
      int mat = col >> 7;
      int hcol = col & 127;
      if (mat == 2) {
        bf16x4 v4;
#pragma unroll
        for (int e = 0; e < 4; ++e) v4[e] = (bf16)(acc[m][n][e] + bvv[n]);
        int t = tloc0 + m * 16 + l4 * 4;
        *(bf16x4*)(Vt + ((size_t)bidx * HH + hcol) * TT + t) = v4;
      } else {
        bf16* dst = (mat == 0) ? kb : qb;
#pragma unroll
        for (int e = 0; e < 4; ++e) {
          size_t rowg = row0 + m * 16 + l4 * 4 + e;
          dst[rowg * HH + hcol] = (bf16)(acc[m][n][e] + bvv[n]);
        }
      }
    }
}

// ---------------- kernel 2: fused causal flash attention -----------------------
// quirk: scores[t][s] = k[t].q[s] -> k rows are the softmax rows (k pre-scaled
// by SCALE*LOG2E, so softmax is computed with exp2 directly).
// grid 512; block 256 = 4 waves * 16 rows = 64-row t-tile.
// Each block runs TWO complementary jobs: tiles (31-p) and (p) -> exactly
// 33 s-iterations per block (perfect balance), all 512 blocks co-resident.
__global__ __launch_bounds__(256, 3) void attn(const bf16* __restrict__ kb,
                                               const bf16* __restrict__ qb,
                                               const bf16* __restrict__ Vt,
                                               float* __restrict__ out) {
  const int bid = blockIdx.x;
  const int b = bid & 31;
  const int p = bid >> 5;                 // 0..15
  const int tid = threadIdx.x;
  const int lane = tid & 63;
  const int w = tid >> 6;
  const int l15 = lane & 15, l4 = lane >> 4;

  __shared__ __attribute__((aligned(16))) bf16 Es[64 * 128];   // q tile [s][h], swizzled
  __shared__ __attribute__((aligned(16))) bf16 Vs[128 * 64];   // Vt tile [h][s], swizzled
  __shared__ __attribute__((aligned(16))) bf16 Ps[4][16 * 72]; // wave-private P

  for (int job = 0; job < 2; ++job) {
    const int tile = job ? p : (31 - p);
    const int t0 = tile * 64;

    // k fragments (A operand, 16 rows per wave) in registers
    bf16x8 af[4];
    {
      const bf16* kp = kb + ((size_t)b * TT + t0 + w * 16 + l15) * HH + l4 * 8;
#pragma unroll
      for (int kc = 0; kc < 4; ++kc) af[kc] = *(const bf16x8*)(kp + kc * 32);
    }

    f32x4 o[8];
#pragma unroll
    for (int j = 0; j < 8; ++j) o[j] = f32x4{0.f, 0.f, 0.f, 0.f};
    float mrow[4], lrow[4];
#pragma unroll
    for (int e = 0; e < 4; ++e) { mrow[e] = -1e30f; lrow[e] = 0.f; }

    const int nst = tile + 1;
    for (int jt = 0; jt < nst; ++jt) {
      const int s0 = jt * 64;
      {
        const bf16* Eg = qb + ((size_t)b * TT + s0) * HH;      // [64][128]
#pragma unroll
        for (int it = 0; it < 4; ++it) {
          int L = w * 256 + it * 64 + lane;                    // chunk id
          int er = L >> 4, ec = L & 15;
          int ecs = ec ^ (er & 7);
          gl_lds16(Eg + er * HH + ecs * 8, Es + (size_t)(w * 256 + it * 64) * 8);
        }
        const bf16* Vg = Vt + (size_t)b * HH * TT + s0;        // rows h, 64 cols
#pragma unroll
        for (int it = 0; it < 4; ++it) {
          int L = w * 256 + it * 64 + lane;
          int vr = L >> 3, vc = L & 7;
          int vcs = vc ^ (vr & 7);
          gl_lds16(Vg + (size_t)vr * TT + vcs * 8, Vs + (size_t)(w * 256 + it * 64) * 8);
        }
      }
      __syncthreads();

      // S = k . q^T   (already in exp2/log2 domain via pre-scaled k)
      f32x4 s[4];
#pragma unroll
      for (int j = 0; j < 4; ++j) s[j] = f32x4{0.f, 0.f, 0.f, 0.f};
#pragma unroll
      for (int kc = 0; kc < 4; ++kc) {
        bf16x8 ef[4];
#pragma unroll
        for (int fn = 0; fn < 4; ++fn) {
          int er = fn * 16 + l15;
          int c = kc * 4 + l4;
          int cs = c ^ (er & 7);
          ef[fn] = *(const bf16x8*)&Es[er * 128 + cs * 8];
        }
#pragma unroll
        for (int fn = 0; fn < 4; ++fn)
          s[fn] = __builtin_amdgcn_mfma_f32_16x16x32_bf16(af[kc], ef[fn],
                                                          s[fn], 0, 0, 0);
      }

      // causal mask (s_glob > t_glob -> -inf)
      if (s0 + 63 > t0 + w * 16) {
#pragma unroll
        for (int fn = 0; fn < 4; ++fn)
#pragma unroll
          for (int e = 0; e < 4; ++e) {
            int tg = t0 + w * 16 + l4 * 4 + e;
            int sg = s0 + fn * 16 + l15;
            if (sg > tg) s[fn][e] = -1e30f;
          }
      }

      // online softmax (log2 domain), defer-max rescale (threshold 8)
      float mx[4];
#pragma unroll
      for (int e = 0; e < 4; ++e) {
        float m = fmaxf(fmaxf(s[0][e], s[1][e]), fmaxf(s[2][e], s[3][e]));
#pragma unroll
        for (int d = 1; d < 16; d <<= 1) m = fmaxf(m, __shfl_xor(m, d));
        mx[e] = m;
      }
      float g = fmaxf(fmaxf(mx[0] - mrow[0], mx[1] - mrow[1]),
                      fmaxf(mx[2] - mrow[2], mx[3] - mrow[3]));
      if (!__all(g <= 8.0f)) {
#pragma unroll
        for (int e = 0; e < 4; ++e) {
          float mn = fmaxf(mrow[e], mx[e]);
          float rsc = exp2f(mrow[e] - mn);
          lrow[e] *= rsc;
#pragma unroll
          for (int fh = 0; fh < 8; ++fh) o[fh][e] *= rsc;
          mrow[e] = mn;
        }
      }
#pragma unroll
      for (int e = 0; e < 4; ++e) {
        float ps = 0.f;
#pragma unroll
        for (int fn = 0; fn < 4; ++fn) {
          float pv = exp2f(s[fn][e] - mrow[e]);
          s[fn][e] = pv;
          ps += pv;
        }
#pragma unroll
        for (int d = 1; d < 16; d <<= 1) ps += __shfl_xor(ps, d);
        lrow[e] += ps;
      }

      // P -> wave-private LDS (bf16), then PV MFMA
#pragma unroll
      for (int fn = 0; fn < 4; ++fn)
#pragma unroll
        for (int e = 0; e < 4; ++e)
          Ps[w][(l4 * 4 + e) * 72 + fn * 16 + l15] = (bf16)s[fn][e];

#pragma unroll
      for (int kc = 0; kc < 2; ++kc) {
        bf16x8 pf = *(const bf16x8*)&Ps[w][l15 * 72 + kc * 32 + l4 * 8];
#pragma unroll
        for (int fh = 0; fh < 8; ++fh) {
          int vr = fh * 16 + l15;
          int c = kc * 4 + l4;
          int cs = c ^ (vr & 7);
          bf16x8 vf = *(const bf16x8*)&Vs[vr * 64 + cs * 8];
          o[fh] = __builtin_amdgcn_mfma_f32_16x16x32_bf16(pf, vf, o[fh], 0, 0, 0);
        }
      }
      __syncthreads();
    }

    // epilogue: O / l -> fp32 out
#pragma unroll
    for (int e = 0; e < 4; ++e) {
      float rl = 1.0f / lrow[e];
      int tg = t0 + w * 16 + l4 * 4 + e;
#pragma unroll
      for (int fh = 0; fh < 8; ++fh)
        out[((size_t)b * TT + tg) * HH + fh * 16 + l15] = o[fh][e] * rl;
    }
  }
}

extern "C" void kernel_launch(void* const* d_in, const int* in_sizes, int n_in,
                              void* d_out, int out_size, void* d_ws, size_t ws_size,
                              hipStream_t stream) {
  (void)in_sizes; (void)n_in; (void)out_size; (void)ws_size;
  const float* x  = (const float*)d_in[0];
  const float* Wk = (const float*)d_in[1];
  const float* bk = (const float*)d_in[2];
  const float* Wq = (const float*)d_in[3];
  const float* bq = (const float*)d_in[4];
  const float* Wv = (const float*)d_in[5];
  const float* bv = (const float*)d_in[6];
  float* out = (float*)d_out;

  const size_t NTH = (size_t)BB * TT * HH;   // 8388608
  bf16* kb = (bf16*)d_ws;
  bf16* qb = kb + NTH;
  bf16* Vt = qb + NTH;
  bf16* Wt = Vt + NTH;                        // 3*128*1024 bf16
  float* bcat = (float*)(Wt + (size_t)3 * HH * DD);

  prep_w<<<192, 256, 0, stream>>>(Wk, Wq, Wv, bk, bq, bv, Wt, bcat);
  qkv_proj<<<1024, 256, 0, stream>>>(x, Wt, bcat, kb, qb, Vt);
  attn<<<512, 256, 0, stream>>>(kb, qb, Vt, out);
}

// Round 7
// 191.718 us; speedup vs baseline: 1.3264x; 1.1026x over previous
//
#include <hip/hip_runtime.h>
#include <hip/hip_bf16.h>
#include <stdint.h>

typedef __bf16 bf16;
typedef __bf16 bf16x8 __attribute__((ext_vector_type(8)));
typedef __bf16 bf16x4 __attribute__((ext_vector_type(4)));
typedef float f32x4 __attribute__((ext_vector_type(4)));
typedef float f32x8 __attribute__((ext_vector_type(8)));

#define BB 32
#define TT 2048
#define DD 1024
#define HH 128
#define SCALE 0.08838834764831845f   // H^-0.5
#define LOG2E 1.4426950408889634f
#define KS (SCALE * LOG2E)

__device__ __forceinline__ void gl_lds16(const bf16* g, bf16* l) {
  __builtin_amdgcn_global_load_lds((__attribute__((address_space(1))) const void*)g,
                                   (__attribute__((address_space(3))) void*)l,
                                   16, 0, 0);
}

// ---------------- kernel 0: Wt[mat][h][d] = W[d][h] (fp32 -> bf16) -------------
// mat 0 (Wk) pre-scaled by SCALE*LOG2E so softmax runs in exp2 domain with no
// extra multiplies. Also emits concatenated fp32 bias bcat[384] (bk scaled).
__global__ __launch_bounds__(256) void prep_w(const float* __restrict__ Wk,
                                              const float* __restrict__ Wq,
                                              const float* __restrict__ Wv,
                                              const float* __restrict__ bk,
                                              const float* __restrict__ bq,
                                              const float* __restrict__ bv,
                                              bf16* __restrict__ Wt,
                                              float* __restrict__ bcat) {
  int tid = blockIdx.x * 256 + threadIdx.x;   // 0..49151
  if (tid < 384) {
    int mat = tid >> 7, h = tid & 127;
    float bb = (mat == 0) ? bk[h] : (mat == 1) ? bq[h] : bv[h];
    bcat[tid] = (mat == 0) ? bb * KS : bb;
  }
  int mat = tid >> 14;
  int r = tid & 16383;
  int h = r & 127;
  int d0 = (r >> 7) << 3;
  const float* W = (mat == 0) ? Wk : (mat == 1) ? Wq : Wv;
  const float ks = (mat == 0) ? KS : 1.0f;
  bf16x8 v;
#pragma unroll
  for (int i = 0; i < 8; ++i) v[i] = (bf16)(W[(size_t)(d0 + i) * HH + h] * ks);
  *(bf16x8*)(Wt + ((size_t)mat * HH + h) * DD + d0) = v;
}

// ---------------- kernel 1: fused QKV projection GEMM (bf16 MFMA) --------------
// Bytes-minimizing shape: BM=256 rows x 384 cols, grid = 256 blocks -> W panel
// (768 KB) is re-fetched only 256x = 201 MB (was 805 MB at BM=64). Total fetch
// ~470 MB at the ~7 TB/s aggregate ceiling -> ~70 us.
// x: reg-staged (fp32 load -> cvt -> ds_write bf16, pad-40 rows = 2-way banks,
//    issued BEFORE W's gl_lds so the auto-wait is vmcnt(3), never draining W).
// W: global_load_lds + XOR swizzle (0 conflicts measured R4/R5).
// 8 waves (2 wave-rows x 4 wave-cols), wave tile 128x96, double-buffer BK=32.
__global__ __launch_bounds__(512, 2) void qkv_proj(
    const float* __restrict__ x, const bf16* __restrict__ Wt,
    const float* __restrict__ bcat,
    bf16* __restrict__ kb, bf16* __restrict__ qb, bf16* __restrict__ Vt) {
  const int bid = blockIdx.x;
  const int tid = threadIdx.x;
  const int lane = tid & 63;
  const int w = tid >> 6;                    // 0..7
  const int wr = w >> 2, wc = w & 3;
  const int l15 = lane & 15, l4 = lane >> 4;
  const size_t row0 = (size_t)bid * 256;
  const int colbase = wc * 96;
  const int rowbase = wr * 128;

  __shared__ __attribute__((aligned(16))) bf16 As[2][256][40];   // 40 KB, pad-40
  __shared__ __attribute__((aligned(16))) bf16 Ws[2][384 * 32];  // 48 KB

  // x staging coords: 512 threads, each owns a half-row (16 cols) of 256x32
  const int sxr = tid >> 1, sxh = (tid & 1) * 16;

  f32x4 acc[8][6];
#pragma unroll
  for (int m = 0; m < 8; ++m)
#pragma unroll
    for (int n = 0; n < 6; ++n) acc[m][n] = f32x4{0.f, 0.f, 0.f, 0.f};

  auto stage_w = [&](int buf, int k0) {
#pragma unroll
    for (int i = 0; i < 3; ++i) {
      int base = i * 512 + (w << 6);            // wave-uniform
      int L = base + lane;
      int col = L >> 2, j = L & 3;              // 4 16B-chunks per 32-col row
      const bf16* src = Wt + (size_t)col * DD + k0 + ((j ^ ((col >> 1) & 3)) << 3);
      gl_lds16(src, &Ws[buf][0] + (size_t)base * 8);
    }
  };
  auto write_x = [&](int buf, f32x8 a0, f32x8 a1) {
    bf16x8 t0, t1;
#pragma unroll
    for (int i = 0; i < 8; ++i) { t0[i] = (bf16)a0[i]; t1[i] = (bf16)a1[i]; }
    *(bf16x8*)&As[buf][sxr][sxh] = t0;
    *(bf16x8*)&As[buf][sxr][sxh + 8] = t1;
  };

  // prologue: stage step 0 into buf 0
  {
    const float* src = x + (row0 + sxr) * DD + sxh;
    f32x8 a0 = *(const f32x8*)src;
    f32x8 a1 = *(const f32x8*)(src + 8);
    stage_w(0, 0);
    write_x(0, a0, a1);
  }
  __syncthreads();

  for (int step = 0; step < 32; ++step) {
    const int cur = step & 1;
    const int k0 = step * 32;

    // issue next-step x loads FIRST (so their wait is vmcnt(3), W stays in flight)
    f32x8 a0, a1;
    if (step < 31) {
      const float* src = x + (row0 + sxr) * DD + k0 + 32 + sxh;
      a0 = *(const f32x8*)src;
      a1 = *(const f32x8*)(src + 8);
      stage_w(cur ^ 1, k0 + 32);
    }

    // compute on buf cur
    bf16x8 bfr[6];
#pragma unroll
    for (int n = 0; n < 6; ++n) {
      int col = colbase + n * 16 + l15;
      bfr[n] = *(const bf16x8*)&Ws[cur][col * 32 + ((l4 ^ ((col >> 1) & 3)) << 3)];
    }
#pragma unroll
    for (int m = 0; m < 8; ++m) {
      int r = rowbase + m * 16 + l15;
      bf16x8 afm = *(const bf16x8*)&As[cur][r][l4 * 8];
#pragma unroll
      for (int n = 0; n < 6; ++n)
        acc[m][n] = __builtin_amdgcn_mfma_f32_16x16x32_bf16(afm, bfr[n],
                                                            acc[m][n], 0, 0, 0);
    }

    if (step < 31) write_x(cur ^ 1, a0, a1);
    __syncthreads();
  }

  // epilogue
  float bvv[6];
#pragma unroll
  for (int n = 0; n < 6; ++n) bvv[n] = bcat[colbase + n * 16 + l15];

  const int bidx = bid >> 3;
  const int tloc0 = (bid & 7) * 256;
#pragma unroll
  for (int m = 0; m < 8; ++m)
#pragma unroll
    for (int n = 0; n < 6; ++n) {
      int col = colbase + n * 16 + l15;
      int mat = col >> 7;
      int hcol = col & 127;
      int rloc = rowbase + m * 16 + l4 * 4;
      if (mat == 2) {
        bf16x4 v4;
#pragma unroll
        for (int e = 0; e < 4; ++e) v4[e] = (bf16)(acc[m][n][e] + bvv[n]);
        *(bf16x4*)(Vt + ((size_t)bidx * HH + hcol) * TT + tloc0 + rloc) = v4;
      } else {
        bf16* dst = (mat == 0) ? kb : qb;
#pragma unroll
        for (int e = 0; e < 4; ++e)
          dst[(row0 + rloc + e) * HH + hcol] = (bf16)(acc[m][n][e] + bvv[n]);
      }
    }
}

// ---------------- kernel 2: fused causal flash attention -----------------------
// quirk: scores[t][s] = k[t].q[s] -> k rows are the softmax rows (k pre-scaled
// by SCALE*LOG2E, so softmax is computed with exp2 directly).
// grid 512; block 256 = 4 waves * 16 rows = 64-row t-tile.
// Each block runs TWO complementary jobs: tiles (31-p) and (p) -> exactly
// 33 s-iterations per block (perfect balance), all 512 blocks co-resident.
__global__ __launch_bounds__(256, 3) void attn(const bf16* __restrict__ kb,
                                               const bf16* __restrict__ qb,
                                               const bf16* __restrict__ Vt,
                                               float* __restrict__ out) {
  const int bid = blockIdx.x;
  const int b = bid & 31;
  const int p = bid >> 5;                 // 0..15
  const int tid = threadIdx.x;
  const int lane = tid & 63;
  const int w = tid >> 6;
  const int l15 = lane & 15, l4 = lane >> 4;

  __shared__ __attribute__((aligned(16))) bf16 Es[64 * 128];   // q tile [s][h], swizzled
  __shared__ __attribute__((aligned(16))) bf16 Vs[128 * 64];   // Vt tile [h][s], swizzled
  __shared__ __attribute__((aligned(16))) bf16 Ps[4][16 * 72]; // wave-private P

  for (int job = 0; job < 2; ++job) {
    const int tile = job ? p : (31 - p);
    const int t0 = tile * 64;

    // k fragments (A operand, 16 rows per wave) in registers
    bf16x8 af[4];
    {
      const bf16* kp = kb + ((size_t)b * TT + t0 + w * 16 + l15) * HH + l4 * 8;
#pragma unroll
      for (int kc = 0; kc < 4; ++kc) af[kc] = *(const bf16x8*)(kp + kc * 32);
    }

    f32x4 o[8];
#pragma unroll
    for (int j = 0; j < 8; ++j) o[j] = f32x4{0.f, 0.f, 0.f, 0.f};
    float mrow[4], lrow[4];
#pragma unroll
    for (int e = 0; e < 4; ++e) { mrow[e] = -1e30f; lrow[e] = 0.f; }

    const int nst = tile + 1;
    for (int jt = 0; jt < nst; ++jt) {
      const int s0 = jt * 64;
      {
        const bf16* Eg = qb + ((size_t)b * TT + s0) * HH;      // [64][128]
#pragma unroll
        for (int it = 0; it < 4; ++it) {
          int L = w * 256 + it * 64 + lane;                    // chunk id
          int er = L >> 4, ec = L & 15;
          int ecs = ec ^ (er & 7);
          gl_lds16(Eg + er * HH + ecs * 8, Es + (size_t)(w * 256 + it * 64) * 8);
        }
        const bf16* Vg = Vt + (size_t)b * HH * TT + s0;        // rows h, 64 cols
#pragma unroll
        for (int it = 0; it < 4; ++it) {
          int L = w * 256 + it * 64 + lane;
          int vr = L >> 3, vc = L & 7;
          int vcs = vc ^ (vr & 7);
          gl_lds16(Vg + (size_t)vr * TT + vcs * 8, Vs + (size_t)(w * 256 + it * 64) * 8);
        }
      }
      __syncthreads();

      // S = k . q^T   (already in exp2/log2 domain via pre-scaled k)
      f32x4 s[4];
#pragma unroll
      for (int j = 0; j < 4; ++j) s[j] = f32x4{0.f, 0.f, 0.f, 0.f};
#pragma unroll
      for (int kc = 0; kc < 4; ++kc) {
        bf16x8 ef[4];
#pragma unroll
        for (int fn = 0; fn < 4; ++fn) {
          int er = fn * 16 + l15;
          int c = kc * 4 + l4;
          int cs = c ^ (er & 7);
          ef[fn] = *(const bf16x8*)&Es[er * 128 + cs * 8];
        }
#pragma unroll
        for (int fn = 0; fn < 4; ++fn)
          s[fn] = __builtin_amdgcn_mfma_f32_16x16x32_bf16(af[kc], ef[fn],
                                                          s[fn], 0, 0, 0);
      }

      // causal mask (s_glob > t_glob -> -inf)
      if (s0 + 63 > t0 + w * 16) {
#pragma unroll
        for (int fn = 0; fn < 4; ++fn)
#pragma unroll
          for (int e = 0; e < 4; ++e) {
            int tg = t0 + w * 16 + l4 * 4 + e;
            int sg = s0 + fn * 16 + l15;
            if (sg > tg) s[fn][e] = -1e30f;
          }
      }

      // online softmax (log2 domain), defer-max rescale (threshold 8)
      float mx[4];
#pragma unroll
      for (int e = 0; e < 4; ++e) {
        float m = fmaxf(fmaxf(s[0][e], s[1][e]), fmaxf(s[2][e], s[3][e]));
#pragma unroll
        for (int d = 1; d < 16; d <<= 1) m = fmaxf(m, __shfl_xor(m, d));
        mx[e] = m;
      }
      float g = fmaxf(fmaxf(mx[0] - mrow[0], mx[1] - mrow[1]),
                      fmaxf(mx[2] - mrow[2], mx[3] - mrow[3]));
      if (!__all(g <= 8.0f)) {
#pragma unroll
        for (int e = 0; e < 4; ++e) {
          float mn = fmaxf(mrow[e], mx[e]);
          float rsc = exp2f(mrow[e] - mn);
          lrow[e] *= rsc;
#pragma unroll
          for (int fh = 0; fh < 8; ++fh) o[fh][e] *= rsc;
          mrow[e] = mn;
        }
      }
#pragma unroll
      for (int e = 0; e < 4; ++e) {
        float ps = 0.f;
#pragma unroll
        for (int fn = 0; fn < 4; ++fn) {
          float pv = exp2f(s[fn][e] - mrow[e]);
          s[fn][e] = pv;
          ps += pv;
        }
#pragma unroll
        for (int d = 1; d < 16; d <<= 1) ps += __shfl_xor(ps, d);
        lrow[e] += ps;
      }

      // P -> wave-private LDS (bf16), then PV MFMA
#pragma unroll
      for (int fn = 0; fn < 4; ++fn)
#pragma unroll
        for (int e = 0; e < 4; ++e)
          Ps[w][(l4 * 4 + e) * 72 + fn * 16 + l15] = (bf16)s[fn][e];

#pragma unroll
      for (int kc = 0; kc < 2; ++kc) {
        bf16x8 pf = *(const bf16x8*)&Ps[w][l15 * 72 + kc * 32 + l4 * 8];
#pragma unroll
        for (int fh = 0; fh < 8; ++fh) {
          int vr = fh * 16 + l15;
          int c = kc * 4 + l4;
          int cs = c ^ (vr & 7);
          bf16x8 vf = *(const bf16x8*)&Vs[vr * 64 + cs * 8];
          o[fh] = __builtin_amdgcn_mfma_f32_16x16x32_bf16(pf, vf, o[fh], 0, 0, 0);
        }
      }
      __syncthreads();
    }

    // epilogue: O / l -> fp32 out
#pragma unroll
    for (int e = 0; e < 4; ++e) {
      float rl = 1.0f / lrow[e];
      int tg = t0 + w * 16 + l4 * 4 + e;
#pragma unroll
      for (int fh = 0; fh < 8; ++fh)
        out[((size_t)b * TT + tg) * HH + fh * 16 + l15] = o[fh][e] * rl;
    }
  }
}

extern "C" void kernel_launch(void* const* d_in, const int* in_sizes, int n_in,
                              void* d_out, int out_size, void* d_ws, size_t ws_size,
                              hipStream_t stream) {
  (void)in_sizes; (void)n_in; (void)out_size; (void)ws_size;
  const float* x  = (const float*)d_in[0];
  const float* Wk = (const float*)d_in[1];
  const float* bk = (const float*)d_in[2];
  const float* Wq = (const float*)d_in[3];
  const float* bq = (const float*)d_in[4];
  const float* Wv = (const float*)d_in[5];
  const float* bv = (const float*)d_in[6];
  float* out = (float*)d_out;

  const size_t NTH = (size_t)BB * TT * HH;   // 8388608
  bf16* kb = (bf16*)d_ws;
  bf16* qb = kb + NTH;
  bf16* Vt = qb + NTH;
  bf16* Wt = Vt + NTH;                        // 3*128*1024 bf16
  float* bcat = (float*)(Wt + (size_t)3 * HH * DD);

  prep_w<<<192, 256, 0, stream>>>(Wk, Wq, Wv, bk, bq, bv, Wt, bcat);
  qkv_proj<<<256, 512, 0, stream>>>(x, Wt, bcat, kb, qb, Vt);
  attn<<<512, 256, 0, stream>>>(kb, qb, Vt, out);
}